// Round 9
// baseline (215.897 us; speedup 1.0000x reference)
//
#include <hip/hip_runtime.h>

#define NROWS  32768
#define DIM    64
#define KCODES 1024
#define NELEM  (NROWS * DIM)   // 2097152
#define CHUNKS 8
#define CPC    (KCODES / CHUNKS)   // 128 codes per chunk-block
#define GROUPS 128                 // row-groups of 256 rows
#define GRID   (GROUPS * CHUNKS)   // 1024 blocks = 4 blocks/CU

typedef float v2f __attribute__((ext_vector_type(2)));

// numpy-style pairwise sum of squares for n=64 contiguous fp32 (contraction
// OFF so squared temps are not fused into adds; matches jnp.sum(w*w)).
// Verified absmax 0.0 in all prior rounds.
__device__ __forceinline__ float np_sumsq64(const float v[64]) {
#pragma clang fp contract(off)
  float r0 = v[0] * v[0];
  float r1 = v[1] * v[1];
  float r2 = v[2] * v[2];
  float r3 = v[3] * v[3];
  float r4 = v[4] * v[4];
  float r5 = v[5] * v[5];
  float r6 = v[6] * v[6];
  float r7 = v[7] * v[7];
#pragma unroll
  for (int i = 8; i < 64; i += 8) {
    r0 += v[i + 0] * v[i + 0];
    r1 += v[i + 1] * v[i + 1];
    r2 += v[i + 2] * v[i + 2];
    r3 += v[i + 3] * v[i + 3];
    r4 += v[i + 4] * v[i + 4];
    r5 += v[i + 5] * v[i + 5];
    r6 += v[i + 6] * v[i + 6];
    r7 += v[i + 7] * v[i + 7];
  }
  return ((r0 + r1) + (r2 + r3)) + ((r4 + r5) + (r6 + r7));
}

// ONE fused kernel + ONE memset. Round-8 accounting: total ~= sum(kernels)
// + ~50us fixed overhead (R5: 108+52; R1: 76+50; R8: 81+49). The dist loop
// family is at its empirical optimum (R1 62.6us = 35us v_pk_fma-4cyc issue
// floor + 27us feed stall; 9 feed/residency variants all >=62.6, M>=2
// always spills: R8 fired both kill signals with a 512-reg budget). So this
// round consolidates launches instead: dist phase is R1's verified config
// VERBATIM (launch_bounds(256,4), pure scalar w-feed, pin, same swizzle,
// grid 1024 = 128 groups x 8 chunks); se folded in-block (own chunk,
// t<128); keys+counters init by one memset (counters start 0xFFFFFFFF ->
// count-up-from--1, finisher sees old==CHUNKS-2); per-group finisher block
// (R5-verified fence/atomic-read rendezvous) writes idx/STE/loss for its
// rows FROM RESIDENT REGISTERS (M=1: thread finishes its own row) — kills
// vq_prep, vq_out (and its 8MB x re-read), and vq_fin.
//
// fp sequences, all op-for-op from absmax-0.0 rounds: dot loop = R1 body;
// sx = R5/R6 v2f np-tree; se = np_sumsq64; d = fma(-2,dot,fl(sx+se[c]));
// strict < over ascending c; u64 (dist_bits<<32)|c atomicMin; STE
// q = x + fl(w - x); loss f64 per-row chain -> wave shfl -> group part ->
// final 128-part reduce (f64 assoc diffs ~1e-15 rel, invisible after the
// f32 cast — R5 verified this exact accumulation shape).
__global__ __launch_bounds__(256, 4)
void vq_fused(const float* __restrict__ x,
              const float* __restrict__ w,
              unsigned long long* __restrict__ keys,
              unsigned int* __restrict__ gcnt,     // [GROUPS], memset 0xFF
              unsigned int* __restrict__ fincnt,   // [1], memset 0xFF
              double* __restrict__ part,           // [GROUPS], no init
              float* __restrict__ outq,
              float* __restrict__ outidx,
              float* __restrict__ outloss) {
  __shared__ float se_lds[CPC];
  __shared__ double sp[4];
  __shared__ int sflag, finflag;

  const int bid = blockIdx.x;
  const int l = (bid & 7) * 128 + (bid >> 3);  // XCD-bijective (R1 swizzle)
  const int group = l >> 3;                    // 0..127 (256 rows each)
  const int chunk = l & 7;                     // 0..7
  const int t = threadIdx.x;
  const int row = group * 256 + t;
  const int c0 = chunk * CPC;

  // se for this block's own chunk (t<128; exact verified tree).
  if (t < CPC) {
    float v[64];
    const float4* wr = (const float4*)(w + (size_t)(c0 + t) * DIM);
#pragma unroll
    for (int i = 0; i < 16; ++i) {
      float4 q = wr[i];
      v[4 * i + 0] = q.x; v[4 * i + 1] = q.y;
      v[4 * i + 2] = q.z; v[4 * i + 3] = q.w;
    }
    se_lds[t] = np_sumsq64(v);
  }

  // Own row -> registers as v2f pairs (R1 prologue + pin).
  v2f xv[32];
  const float4* xr = (const float4*)(x + (size_t)row * DIM);
#pragma unroll
  for (int i = 0; i < 16; ++i) {
    float4 q = xr[i];
    xv[2 * i + 0] = (v2f){q.x, q.y};
    xv[2 * i + 1] = (v2f){q.z, q.w};
  }
#pragma unroll
  for (int i = 0; i < 32; ++i) asm volatile("" : "+v"(xv[i]));  // opaque pin

  // sx via the verified np tree in v2f form (R5/R6, absmax 0.0).
  float sx;
  {
#pragma clang fp contract(off)
    v2f A0 = xv[0] * xv[0], A1 = xv[1] * xv[1];
    v2f A2 = xv[2] * xv[2], A3 = xv[3] * xv[3];
#pragma unroll
    for (int m = 1; m < 8; ++m) {
      A0 += xv[4 * m + 0] * xv[4 * m + 0];
      A1 += xv[4 * m + 1] * xv[4 * m + 1];
      A2 += xv[4 * m + 2] * xv[4 * m + 2];
      A3 += xv[4 * m + 3] * xv[4 * m + 3];
    }
    sx = ((A0.x + A0.y) + (A1.x + A1.y)) + ((A2.x + A2.y) + (A3.x + A3.y));
  }

  __syncthreads();

  // Dist loop: R1 verbatim (pure scalar w-feed, se from LDS).
  const float4* w4 = (const float4*)w;
  float bd = __builtin_inff();
  int bc = 0;

#pragma unroll 2
  for (int j = 0; j < CPC; ++j) {
    const int c = c0 + j;                      // wave-uniform -> scalar loads
    const float4* wr = w4 + (size_t)c * 16;
    v2f a0 = (v2f){0.f, 0.f}, a1 = (v2f){0.f, 0.f};
    v2f a2 = (v2f){0.f, 0.f}, a3 = (v2f){0.f, 0.f};
#pragma unroll
    for (int i = 0; i < 16; i += 2) {
      float4 t0 = wr[i];
      float4 t1 = wr[i + 1];
      a0 += (v2f){t0.x, t0.y} * xv[2 * i + 0];   // v_pk_fma_f32
      a1 += (v2f){t0.z, t0.w} * xv[2 * i + 1];
      a2 += (v2f){t1.x, t1.y} * xv[2 * i + 2];
      a3 += (v2f){t1.z, t1.w} * xv[2 * i + 3];
    }
    v2f s01 = a0 + a1;
    v2f s23 = a2 + a3;
    v2f s = s01 + s23;
    float dot = s.x + s.y;
    float d = fmaf(-2.0f, dot, sx + se_lds[j]);
    if (d < bd) { bd = d; bc = c; }
  }

  atomicMin(&keys[row], ((unsigned long long)__float_as_uint(bd) << 32) |
                            (unsigned long long)(unsigned)bc);

  // Group rendezvous (counters pre-set to 0xFFFFFFFF by the memset; arrivals
  // see old = -1,0,..,CHUNKS-2 -> the 8th sees CHUNKS-2).
  __threadfence();
  if (t == 0) {
    unsigned int old = atomicAdd(&gcnt[group], 1u);
    sflag = (old == (unsigned int)(CHUNKS - 2)) ? 1 : 0;
  }
  __syncthreads();
  if (!sflag) return;
  __threadfence();   // acquire: all chunks' atomicMins visible

  // Finisher: each thread emits ITS OWN resident row (R5-verified pattern).
  unsigned long long k = atomicMin(&keys[row], ~0ull);  // coherent read
  const int idx = (int)(unsigned int)(k & 0xFFFFFFFFull);
  outidx[row] = (float)idx;

  double acc = 0.0;
  {
    const float4* wr = (const float4*)(w + (size_t)idx * DIM);
    float4* oq = (float4*)(outq + (size_t)row * DIM);
#pragma unroll
    for (int i = 0; i < 16; ++i) {
      float4 wv = wr[i];
      const v2f xlo = xv[2 * i], xhi = xv[2 * i + 1];
      float tx = wv.x - xlo.x, ty = wv.y - xlo.y;
      float tz = wv.z - xhi.x, tw = wv.w - xhi.y;
      float4 q;
      q.x = xlo.x + tx; q.y = xlo.y + ty;   // ref STE: x + fl(w - x)
      q.z = xhi.x + tz; q.w = xhi.y + tw;
      oq[i] = q;
      acc += (double)tx * tx + (double)ty * ty + (double)tz * tz + (double)tw * tw;
    }
  }

#pragma unroll
  for (int s = 32; s > 0; s >>= 1) acc += __shfl_down(acc, s, 64);
  if ((t & 63) == 0) sp[t >> 6] = acc;
  __syncthreads();
  if (t == 0) {
    part[group] = (sp[0] + sp[1]) + (sp[2] + sp[3]);
    __threadfence();
    unsigned int old = atomicAdd(fincnt, 1u);
    finflag = (old == (unsigned int)(GROUPS - 2)) ? 1 : 0;
  }
  __syncthreads();
  if (!finflag) return;
  __threadfence();

  // Last finisher: reduce the 128 group partials (coherent atomic reads).
  double a = (t < GROUPS) ? atomicAdd(&part[t], 0.0) : 0.0;
#pragma unroll
  for (int s = 32; s > 0; s >>= 1) a += __shfl_down(a, s, 64);
  __syncthreads();                              // sp[] reuse
  if ((t & 63) == 0) sp[t >> 6] = a;
  __syncthreads();
  if (t == 0) {
    double total = (sp[0] + sp[1]) + (sp[2] + sp[3]);
    *outloss = 0.5f * (float)(total / (double)NELEM);
  }
}

extern "C" void kernel_launch(void* const* d_in, const int* in_sizes, int n_in,
                              void* d_out, int out_size, void* d_ws, size_t ws_size,
                              hipStream_t stream) {
  const float* x = (const float*)d_in[0];   // inputs (32,64,32,32) fp32
  const float* w = (const float*)d_in[1];   // weight (1024,64) fp32

  float* outq    = (float*)d_out;           // [0, 2097152)
  float* outidx  = outq + NELEM;            // [2097152, +32768)
  float* outloss = outidx + NROWS;          // [2129920]

  char* wsb = (char*)d_ws;
  unsigned long long* keys = (unsigned long long*)wsb;           // 256 KB
  unsigned int* gcnt   = (unsigned int*)(wsb + 262144);          // 512 B
  unsigned int* fincnt = (unsigned int*)(wsb + 262144 + 512);    // 4 B
  double* part = (double*)(wsb + 263168);                        // 1 KB

  // keys -> 0xFF..F (+inf u64 keys); gcnt/fincnt -> 0xFFFFFFFF (count from -1).
  hipMemsetAsync(wsb, 0xFF, 262144 + 512 + 64, stream);
  hipLaunchKernelGGL(vq_fused, dim3(GRID), dim3(256), 0, stream,
                     x, w, keys, gcnt, fincnt, part, outq, outidx, outloss);
}